// Round 8
// baseline (270.887 us; speedup 1.0000x reference)
//
#include <hip/hip_runtime.h>
#include <stdint.h>

#define S_   512
#define E_   512
#define CIN  1536
#define P_   32768
#define OUTC 512
#define LDP  40    // padded LDS row stride (shorts) for gemm2 A tile
#define CSTR 136   // epilogue C-staging row stride (shorts)

typedef __attribute__((ext_vector_type(8))) short s16x8;   // MFMA A/B frag (8 bf16)
typedef __attribute__((ext_vector_type(4))) float f32x4;   // MFMA C/D frag
typedef unsigned short ushort_t;

__device__ __forceinline__ float b2f(uint32_t b) {
    union { uint32_t u; float f; } v; v.u = b << 16; return v.f;
}
__device__ __forceinline__ uint32_t f2b(float f) {   // fp32 -> bf16 bits, RNE
    union { float f; uint32_t u; } v; v.f = f;
    return (v.u + 0x7fffu + ((v.u >> 16) & 1u)) >> 16;
}
__device__ __forceinline__ void async16(const void* g, void* l) {
    __builtin_amdgcn_global_load_lds(
        (const __attribute__((address_space(1))) void*)g,
        (__attribute__((address_space(3))) void*)l, 16, 0, 0);
}
// branchless top-3 insert
__device__ __forceinline__ void ins3(float d, int s,
                                     float& d0, int& i0, float& d1, int& i1,
                                     float& d2, int& i2)
{
    const bool c0 = d < d0, c1 = d < d1, c2 = d < d2;
    i2 = c1 ? i1 : (c2 ? s : i2);  d2 = c1 ? d1 : (c2 ? d : d2);
    i1 = c0 ? i0 : (c1 ? s : i1);  d1 = c0 ? d0 : (c1 ? d : d1);
    i0 = c0 ? s  : i0;             d0 = c0 ? d  : d0;
}

// ---------- 1) prologue: knn + W1/W2 cvt + Hcat cvt + stats zero ----------
__global__ __launch_bounds__(256) void prologue_kernel(
    const float* __restrict__ xyz, const float* __restrict__ centers,
    const float* __restrict__ W1f, const float* __restrict__ W2f,
    const float* __restrict__ H4, const float* __restrict__ H8,
    const float* __restrict__ H12,
    ushort_t* __restrict__ W1c, ushort_t* __restrict__ W2c,
    ushort_t* __restrict__ Hcat,
    int* __restrict__ idx_out, float* __restrict__ w_out, float* __restrict__ stats)
{
    __shared__ float4 c4[S_];
    const int blk = blockIdx.x;
    const int t   = threadIdx.x;

    if (blk >= 512) {
        if (blk < 1280) {          // W1: 196608 vec4 over 768 blocks
            const int v = (blk - 512) * 256 + t;
            const float4 x = ((const float4*)W1f)[v];
            uint2 o; o.x = f2b(x.x) | (f2b(x.y) << 16); o.y = f2b(x.z) | (f2b(x.w) << 16);
            ((uint2*)W1c)[v] = o;
        } else if (blk < 1536) {   // W2: 65536 vec4 over 256 blocks
            const int v = (blk - 1280) * 256 + t;
            const float4 x = ((const float4*)W2f)[v];
            uint2 o; o.x = f2b(x.x) | (f2b(x.y) << 16); o.y = f2b(x.z) | (f2b(x.w) << 16);
            ((uint2*)W2c)[v] = o;
        } else if (blk == 1536) {   // zero 2048-float stats
#pragma unroll
            for (int i = 0; i < 8; ++i) stats[t * 8 + i] = 0.f;
        } else {                    // Hcat: 786432 vec4 over 3072 blocks
            const int hv = (blk - 1537) * 256 + t;      // vec4 index into Hcat
            const int r  = hv / 384;                     // row = b*512+s
            const int e  = (hv - r * 384) * 4;           // col in [0,1536)
            const int sel = e >> 9, off = e & 511;
            const float* src = (sel == 0) ? H4 : (sel == 1) ? H8 : H12;
            const float4 x = *(const float4*)&src[(size_t)r * 512 + off];
            uint2 o; o.x = f2b(x.x) | (f2b(x.y) << 16); o.y = f2b(x.z) | (f2b(x.w) << 16);
            ((uint2*)Hcat)[hv] = o;
        }
        return;
    }

    // ---- kNN: 4 lanes/point, stride-4 interleaved scan, branchless ----
    const int pBlock = blk * 64;
    const int b = pBlock >> 13;
    for (int i = t; i < S_; i += 256) {
        const float x = centers[(size_t)(b * S_ + i) * 3 + 0];
        const float y = centers[(size_t)(b * S_ + i) * 3 + 1];
        const float z = centers[(size_t)(b * S_ + i) * 3 + 2];
        float4 v; v.x = x; v.y = y; v.z = z; v.w = x * x + y * y + z * z;
        c4[i] = v;
    }
    __syncthreads();

    const int l4 = t & 3, pi = t >> 2;
    const int p = pBlock + pi;
    const float x = xyz[(size_t)p * 3 + 0];
    const float y = xyz[(size_t)p * 3 + 1];
    const float z = xyz[(size_t)p * 3 + 2];
    const float xx = x * x + y * y + z * z;

    float d0 = 3e38f, d1 = 3e38f, d2 = 3e38f;
    int   i0 = 0,     i1 = 0,     i2 = 0;
#pragma unroll 2
    for (int j = 0; j < 128; ++j) {
        const int s = 4 * j + l4;
        const float4 c = c4[s];
        const float dot = x * c.x + y * c.y + z * c.z;
        const float d = (xx - 2.0f * dot) + c.w;   // mirror np association
        ins3(d, s, d0, i0, d1, i1, d2, i2);
    }
#pragma unroll
    for (int m = 1; m <= 2; m <<= 1) {
        const float od0 = __shfl_xor(d0, m), od1 = __shfl_xor(d1, m), od2 = __shfl_xor(d2, m);
        const int   oi0 = __shfl_xor(i0, m), oi1 = __shfl_xor(i1, m), oi2 = __shfl_xor(i2, m);
        ins3(od0, oi0, d0, i0, d1, i1, d2, i2);
        ins3(od1, oi1, d0, i0, d1, i1, d2, i2);
        ins3(od2, oi2, d0, i0, d1, i1, d2, i2);
    }
    if (l4 == 0) {
        const float r0 = 1.0f / (d0 + 1e-8f);
        const float r1 = 1.0f / (d1 + 1e-8f);
        const float r2 = 1.0f / (d2 + 1e-8f);
        const float rs = r0 + r1 + r2;
        idx_out[p * 3 + 0] = i0; idx_out[p * 3 + 1] = i1; idx_out[p * 3 + 2] = i2;
        w_out[p * 3 + 0] = r0 / rs; w_out[p * 3 + 1] = r1 / rs; w_out[p * 3 + 2] = r2 / rs;
    }
}

// ---------- 2) G = Hcat(2048x1536 bf16) x W1c^T -> fp32 [2048,512] ----------
// Pure-DMA staging (no VALU in staging phase), 64x64 tiles, 256 blocks.
__global__ __launch_bounds__(256) void gemm_g(
    const ushort_t* __restrict__ Hcat, const ushort_t* __restrict__ W1c,
    float* __restrict__ G)
{
    __shared__ __align__(16) ushort_t Asm[64 * 32];   // 4 KB, DMA layout
    __shared__ __align__(16) ushort_t Bsm[64 * 32];
    const int t = threadIdx.x, wave = t >> 6, lane = t & 63;
    const int wr = wave >> 1, wc = wave & 1, quad = lane >> 4, l15 = lane & 15;
    const int colBase = blockIdx.x * 64, rowBase = blockIdx.y * 64;

    f32x4 acc[2][2];
    const f32x4 z4 = {0.f, 0.f, 0.f, 0.f};
#pragma unroll
    for (int i = 0; i < 2; ++i)
#pragma unroll
        for (int j = 0; j < 2; ++j) acc[i][j] = z4;

    const int ar = t >> 2, ac = (t & 3) * 8;   // 256 slots = 64 rows x 4 chunks
    const ushort_t* Ab = Hcat + (size_t)rowBase * CIN;
    const ushort_t* Bb = W1c  + (size_t)colBase * CIN;

    for (int k0 = 0; k0 < CIN; k0 += 32) {
        async16(Ab + (size_t)ar * CIN + k0 + ac, &Asm[(size_t)t * 8]);
        async16(Bb + (size_t)ar * CIN + k0 + ac, &Bsm[(size_t)t * 8]);
        __syncthreads();

        s16x8 af[2], bfr[2];
#pragma unroll
        for (int mi = 0; mi < 2; ++mi)
            af[mi] = *(const s16x8*)&Asm[(wr * 32 + mi * 16 + l15) * 32 + quad * 8];
#pragma unroll
        for (int ni = 0; ni < 2; ++ni)
            bfr[ni] = *(const s16x8*)&Bsm[(wc * 32 + ni * 16 + l15) * 32 + quad * 8];
#pragma unroll
        for (int mi = 0; mi < 2; ++mi)
#pragma unroll
            for (int ni = 0; ni < 2; ++ni)
                acc[mi][ni] = __builtin_amdgcn_mfma_f32_16x16x32_bf16(
                    af[mi], bfr[ni], acc[mi][ni], 0, 0, 0);
        __syncthreads();
    }

#pragma unroll
    for (int mi = 0; mi < 2; ++mi) {
        const int row0 = rowBase + wr * 32 + mi * 16 + quad * 4;
#pragma unroll
        for (int ni = 0; ni < 2; ++ni) {
            const int col = colBase + wc * 32 + ni * 16 + l15;
#pragma unroll
            for (int r = 0; r < 4; ++r)
                G[(size_t)(row0 + r) * OUTC + col] = acc[mi][ni][r];
        }
    }
}

// ---------- 3) blend: C1raw[p] = sum_k w_k * G[b,i_k] (fp32) -> bf16 + BN1 stats ----------
__global__ __launch_bounds__(256) void blend1(
    const float* __restrict__ G, const int* __restrict__ idx, const float* __restrict__ wgt,
    ushort_t* __restrict__ C1, float* __restrict__ gsum, float* __restrict__ gsq)
{
    __shared__ float reds[512], redq[512];
    const int t = threadIdx.x;
    const int cg = t & 63, pr = t >> 6;
    const int ch0 = cg * 8;
    const int pBase = blockIdx.x * 128;

    float s[8], q[8];
#pragma unroll
    for (int e = 0; e < 8; ++e) { s[e] = 0.f; q[e] = 0.f; }

    for (int j = 0; j < 32; ++j) {
        const int p = pBase + j * 4 + pr;
        const int b = p >> 13;
        const int i0 = idx[p * 3 + 0], i1 = idx[p * 3 + 1], i2 = idx[p * 3 + 2];
        const float w0 = wgt[p * 3 + 0], w1 = wgt[p * 3 + 1], w2 = wgt[p * 3 + 2];
        const float* g0 = G + ((size_t)b * S_ + i0) * OUTC + ch0;
        const float* g1 = G + ((size_t)b * S_ + i1) * OUTC + ch0;
        const float* g2 = G + ((size_t)b * S_ + i2) * OUTC + ch0;
        float c[8];
        uint32_t od[4];
#pragma unroll
        for (int e = 0; e < 8; ++e) {
            c[e] = w0 * g0[e] + w1 * g1[e] + w2 * g2[e];
            s[e] += c[e]; q[e] += c[e] * c[e];
        }
#pragma unroll
        for (int e = 0; e < 4; ++e) od[e] = f2b(c[2 * e]) | (f2b(c[2 * e + 1]) << 16);
        uint4 o; o.x = od[0]; o.y = od[1]; o.z = od[2]; o.w = od[3];
        *(uint4*)(C1 + (size_t)p * OUTC + ch0) = o;
    }

    for (int i = t; i < 512; i += 256) { reds[i] = 0.f; redq[i] = 0.f; }
    __syncthreads();
#pragma unroll
    for (int e = 0; e < 8; ++e) {
        atomicAdd(&reds[ch0 + e], s[e]);
        atomicAdd(&redq[ch0 + e], q[e]);
    }
    __syncthreads();
    for (int i = t; i < 512; i += 256) {
        atomicAdd(&gsum[i], reds[i]);
        atomicAdd(&gsq[i],  redq[i]);
    }
}

// ---------- 4) GEMM2: BN1+ReLU fused on A (pipelined out of staging phase) ----------
__global__ __launch_bounds__(256) void gemm2_fused(
    const ushort_t* __restrict__ Araw, const ushort_t* __restrict__ Bw,
    float* __restrict__ outF, ushort_t* __restrict__ outB, int out_bf16,
    const float* __restrict__ gsum1, const float* __restrict__ gsq1,
    const float* __restrict__ g1, const float* __restrict__ be1,
    float* __restrict__ gsum2, float* __restrict__ gsq2)
{
    __shared__ __align__(16) ushort_t sbuf[9216];   // Asm(5120) + Bsm(4096); epilogue reuse
    __shared__ __align__(16) float sc1[512];
    __shared__ __align__(16) float sh1[512];
    __shared__ float red[256];
    ushort_t* Asm = sbuf;                 // 128 x LDP(40), padded, register-staged
    ushort_t* Bsm = sbuf + 128 * LDP;     // 128 x 32, DMA layout

    const int K = 512, Nn = 512;
    const int t = threadIdx.x, wave = t >> 6, lane = t & 63;
    const int wr = wave >> 1, wc = wave & 1, quad = lane >> 4, l15 = lane & 15;
    const int rowBase = blockIdx.x * 128, colBase = blockIdx.y * 128;

    const float inv = 1.0f / (float)P_;
    for (int i = t; i < 512; i += 256) {
        const float mean = gsum1[i] * inv;
        const float var  = gsq1[i] * inv - mean * mean;
        const float s    = g1[i] * rsqrtf(var + 1e-5f);
        sc1[i] = s; sh1[i] = be1[i] - mean * s;
    }

    f32x4 acc[4][4];
    const f32x4 z4 = {0.f, 0.f, 0.f, 0.f};
#pragma unroll
    for (int i = 0; i < 4; ++i)
#pragma unroll
        for (int j = 0; j < 4; ++j) acc[i][j] = z4;

    const int ar0 = t >> 2, ac0 = (t & 3) * 8;
    const int ar1 = ar0 + 64;
    const ushort_t* Ab = Araw + (size_t)rowBase * K;
    const ushort_t* Bb = Bw   + (size_t)colBase * K;

    // BN1 transform of a 16B A chunk (channels cb..cb+7), fp32 math, RNE to bf16
    auto bn1pack = [&](int cb, uint4 a, uint4& u) {
        const float4 sA = *(const float4*)&sc1[cb];
        const float4 sB = *(const float4*)&sc1[cb + 4];
        const float4 hA = *(const float4*)&sh1[cb];
        const float4 hB = *(const float4*)&sh1[cb + 4];
        u.x = f2b(fmaxf(0.f, b2f(a.x & 0xffffu) * sA.x + hA.x)) |
              (f2b(fmaxf(0.f, b2f(a.x >> 16)     * sA.y + hA.y)) << 16);
        u.y = f2b(fmaxf(0.f, b2f(a.y & 0xffffu) * sA.z + hA.z)) |
              (f2b(fmaxf(0.f, b2f(a.y >> 16)     * sA.w + hA.w)) << 16);
        u.z = f2b(fmaxf(0.f, b2f(a.z & 0xffffu) * sB.x + hB.x)) |
              (f2b(fmaxf(0.f, b2f(a.z >> 16)     * sB.y + hB.y)) << 16);
        u.w = f2b(fmaxf(0.f, b2f(a.w & 0xffffu) * sB.z + hB.z)) |
              (f2b(fmaxf(0.f, b2f(a.w >> 16)     * sB.w + hB.w)) << 16);
    };

    uint4 aR0 = *(const uint4*)(Ab + (size_t)ar0 * K + ac0);
    uint4 aR1 = *(const uint4*)(Ab + (size_t)ar1 * K + ac0);
    __syncthreads();    // sc1/sh1 visible
    uint4 u0, u1;
    bn1pack(ac0, aR0, u0);
    bn1pack(ac0, aR1, u1);

    for (int k0 = 0; k0 < K; k0 += 32) {
        // staging phase: just 2 ds_write_b128 + 2 DMA (no VALU transform here)
        *(uint4*)&Asm[ar0 * LDP + ac0] = u0;
        *(uint4*)&Asm[ar1 * LDP + ac0] = u1;
        async16(Bb + (size_t)ar0 * K + k0 + ac0, &Bsm[(size_t)t * 8]);
        async16(Bb + (size_t)ar1 * K + k0 + ac0, &Bsm[(size_t)(t + 256) * 8]);
        __syncthreads();

        if (k0 + 32 < K) {   // prefetch next raw A (overlaps MFMA)
            aR0 = *(const uint4*)(Ab + (size_t)ar0 * K + k0 + 32 + ac0);
            aR1 = *(const uint4*)(Ab + (size_t)ar1 * K + k0 + 32 + ac0);
        }

        s16x8 af[4], bfr[4];
#pragma unroll
        for (int mi = 0; mi < 4; ++mi)
            af[mi] = *(const s16x8*)&Asm[(wr * 64 + mi * 16 + l15) * LDP + quad * 8];
#pragma unroll
        for (int ni = 0; ni < 4; ++ni)
            bfr[ni] = *(const s16x8*)&Bsm[(wc * 64 + ni * 16 + l15) * 32 + quad * 8];
#pragma unroll
        for (int mi = 0; mi < 4; ++mi)
#pragma unroll
            for (int ni = 0; ni < 4; ++ni)
                acc[mi][ni] = __builtin_amdgcn_mfma_f32_16x16x32_bf16(
                    af[mi], bfr[ni], acc[mi][ni], 0, 0, 0);

        if (k0 + 32 < K) {   // transform next chunk while MFMA pipe drains
            bn1pack(k0 + 32 + ac0, aR0, u0);
            bn1pack(k0 + 32 + ac0, aR1, u1);
        }
        __syncthreads();   // frag reads done before next stage overwrites
    }

    // ---- BN2 stats ----
    red[t] = 0.f;
    __syncthreads();
#pragma unroll
    for (int ni = 0; ni < 4; ++ni) {
        float s = 0.f, q = 0.f;
#pragma unroll
        for (int mi = 0; mi < 4; ++mi)
#pragma unroll
            for (int r = 0; r < 4; ++r) { const float v = acc[mi][ni][r]; s += v; q += v * v; }
        const int cl = wc * 64 + ni * 16 + l15;
        atomicAdd(&red[cl], s);
        atomicAdd(&red[128 + cl], q);
    }
    __syncthreads();
    if (t < 128) atomicAdd(&gsum2[colBase + t], red[t]);
    else         atomicAdd(&gsq2[colBase + (t - 128)], red[t]);

    // ---- store ----
    if (out_bf16) {
        ushort_t* cst = sbuf;          // 64 x CSTR(136) = 8704 shorts
        const int rr = t >> 2, seg = t & 3;
#pragma unroll
        for (int c = 0; c < 2; ++c) {
            __syncthreads();
            if (wr == c) {
#pragma unroll
                for (int mi = 0; mi < 4; ++mi)
#pragma unroll
                    for (int ni = 0; ni < 4; ++ni)
#pragma unroll
                        for (int r = 0; r < 4; ++r)
                            cst[(mi * 16 + quad * 4 + r) * CSTR + wc * 64 + ni * 16 + l15] =
                                (ushort_t)f2b(acc[mi][ni][r]);
            }
            __syncthreads();
            const size_t gbase = (size_t)(rowBase + c * 64 + rr) * Nn + colBase + seg * 32;
#pragma unroll
            for (int i = 0; i < 4; ++i) {
                const uint4 v = *(const uint4*)&cst[rr * CSTR + seg * 32 + i * 8];
                *(uint4*)(outB + gbase + i * 8) = v;
            }
        }
    } else {
#pragma unroll
        for (int mi = 0; mi < 4; ++mi) {
            const int row0 = rowBase + wr * 64 + mi * 16 + quad * 4;
#pragma unroll
            for (int ni = 0; ni < 4; ++ni) {
                const int col = colBase + wc * 64 + ni * 16 + l15;
#pragma unroll
                for (int r = 0; r < 4; ++r)
                    outF[(size_t)(row0 + r) * Nn + col] = acc[mi][ni][r];
            }
        }
    }
}

// ---------- 5) BN2 finalize (inline) + apply + ReLU -> d_out fp32 ----------
__global__ __launch_bounds__(256) void bn_apply_out(
    const ushort_t* __restrict__ C2, float* __restrict__ Y,
    const float* __restrict__ gsum, const float* __restrict__ gsq,
    const float* __restrict__ gamma, const float* __restrict__ beta, int from_bf16)
{
    __shared__ float sc[512], sh[512];
    const int t = threadIdx.x;
    const float inv = 1.0f / (float)P_;
    for (int i = t; i < 512; i += 256) {
        const float mean = gsum[i] * inv;
        const float var  = gsq[i] * inv - mean * mean;
        const float s    = gamma[i] * rsqrtf(var + 1e-5f);
        sc[i] = s; sh[i] = beta[i] - mean * s;
    }
    __syncthreads();
    const size_t v = (size_t)blockIdx.x * 256 + t;   // 8 elems/thread
    const int ch = (int)((v * 8) & 511);
    float4 u0, u1;
    if (from_bf16) {
        const uint4 xv = ((const uint4*)C2)[v];
        u0.x = b2f(xv.x & 0xffffu); u0.y = b2f(xv.x >> 16);
        u0.z = b2f(xv.y & 0xffffu); u0.w = b2f(xv.y >> 16);
        u1.x = b2f(xv.z & 0xffffu); u1.y = b2f(xv.z >> 16);
        u1.z = b2f(xv.w & 0xffffu); u1.w = b2f(xv.w >> 16);
    } else {
        u0 = ((const float4*)Y)[v * 2];
        u1 = ((const float4*)Y)[v * 2 + 1];
    }
    u0.x = fmaxf(0.f, u0.x * sc[ch + 0] + sh[ch + 0]);
    u0.y = fmaxf(0.f, u0.y * sc[ch + 1] + sh[ch + 1]);
    u0.z = fmaxf(0.f, u0.z * sc[ch + 2] + sh[ch + 2]);
    u0.w = fmaxf(0.f, u0.w * sc[ch + 3] + sh[ch + 3]);
    u1.x = fmaxf(0.f, u1.x * sc[ch + 4] + sh[ch + 4]);
    u1.y = fmaxf(0.f, u1.y * sc[ch + 5] + sh[ch + 5]);
    u1.z = fmaxf(0.f, u1.z * sc[ch + 6] + sh[ch + 6]);
    u1.w = fmaxf(0.f, u1.w * sc[ch + 7] + sh[ch + 7]);
    ((float4*)Y)[v * 2]     = u0;
    ((float4*)Y)[v * 2 + 1] = u1;
}

// ---------- launch ----------
extern "C" void kernel_launch(void* const* d_in, const int* in_sizes, int n_in,
                              void* d_out, int out_size, void* d_ws, size_t ws_size,
                              hipStream_t stream)
{
    (void)in_sizes; (void)n_in; (void)out_size;
    const float* xyzF = (const float*)d_in[0];
    const float* cenF = (const float*)d_in[1];
    const float* H4   = (const float*)d_in[2];
    const float* H8   = (const float*)d_in[3];
    const float* H12  = (const float*)d_in[4];
    const float* W1f  = (const float*)d_in[5];
    // b1 (d_in[6]) / b2 (d_in[10]) cancel in BN mean subtraction
    const float* g1F  = (const float*)d_in[7];
    const float* be1F = (const float*)d_in[8];
    const float* W2f  = (const float*)d_in[9];
    const float* g2F  = (const float*)d_in[11];
    const float* be2F = (const float*)d_in[12];

    char* w = (char*)d_ws;
    float*    stats = (float*)w;     w += 2048 * 4;
    ushort_t* W1c   = (ushort_t*)w;  w += (size_t)OUTC * CIN * 2;
    ushort_t* W2c   = (ushort_t*)w;  w += (size_t)OUTC * OUTC * 2;
    int*      idxb  = (int*)w;       w += (size_t)P_ * 3 * 4;
    float*    wb    = (float*)w;     w += (size_t)P_ * 3 * 4;
    float*    G     = (float*)w;     w += (size_t)2048 * OUTC * 4;     // 4 MB
    ushort_t* C1    = (ushort_t*)w;  w += (size_t)P_ * OUTC * 2;       // 32 MB (raw, pre-BN)
    ushort_t* Hcat  = C1;            // alias: Hcat (6 MB) dead before blend1 writes C1
    const size_t need1 = (size_t)(w - (char*)d_ws);
    const int out_bf16 = (ws_size >= need1 + (size_t)P_ * OUTC * 2) ? 1 : 0;
    ushort_t* C2 = (ushort_t*)w;     // only used when out_bf16
    float* sum1 = stats, *sq1 = stats + 512, *sum2 = stats + 1024, *sq2 = stats + 1536;

    prologue_kernel<<<4609, 256, 0, stream>>>(xyzF, cenF, W1f, W2f, H4, H8, H12,
                                              W1c, W2c, Hcat, idxb, wb, stats);
    gemm_g<<<dim3(8, 32), 256, 0, stream>>>(Hcat, W1c, G);
    blend1<<<P_ / 128, 256, 0, stream>>>(G, idxb, wb, C1, sum1, sq1);
    gemm2_fused<<<dim3(P_ / 128, 4), 256, 0, stream>>>(C1, W2c, (float*)d_out, C2, out_bf16,
                                                       sum1, sq1, g1F, be1F, sum2, sq2);
    bn_apply_out<<<(P_ * OUTC / 8) / 256, 256, 0, stream>>>(C2, (float*)d_out, sum2, sq2,
                                                            g2F, be2F, out_bf16);
}